// Round 12
// baseline (2201.878 us; speedup 1.0000x reference)
//
#include <hip/hip_runtime.h>

typedef unsigned short u16;
typedef unsigned int   u32;
typedef __bf16 bf16x8 __attribute__((ext_vector_type(8)));
typedef float  f32x4  __attribute__((ext_vector_type(4)));
typedef int    i32x4  __attribute__((ext_vector_type(4)));
typedef u32    u32x2  __attribute__((ext_vector_type(2)));

#define Bn 8
#define Sn 96
#define Tn 96
#define Hn 64
#define H2n 128
#define NDIAG 191
#define NROUND 192
#define STR 72            // state row stride (u16): 144B, 16B-aligned
#define ARR (Sn*STR)      // 6912 u16 per state array; 8 arrays = 110,592 B dynamic LDS

__device__ __forceinline__ float bf2f(u16 u){ return __uint_as_float(((u32)u)<<16); }
__device__ __forceinline__ u16 f2bf_rne(float f){
  u32 u = __float_as_uint(f);
  u += 0x7FFFu + ((u>>16)&1u);
  return (u16)(u>>16);
}
// HW packed fp32->bf16 (RNE): dst = { bf16(b)<<16 | bf16(a) }
__device__ __forceinline__ u32 cvt_pk_bf16(float a, float b){
  u32 r;
  asm("v_cvt_pk_bf16_f32 %0, %1, %2" : "=v"(r) : "v"(a), "v"(b));
  return r;
}
__device__ __forceinline__ float lo16f(u32 u){ return __uint_as_float(u << 16); }
__device__ __forceinline__ float hi16f(u32 u){ return __uint_as_float(u & 0xFFFF0000u); }
__device__ __forceinline__ float fast_tanh(float x){
  float y = fminf(fmaxf(x+x, -30.f), 30.f);
  float e = __expf(y);
  return (e-1.f)*__builtin_amdgcn_rcpf(e+1.f);
}
// Workgroup barrier WITHOUT the vmcnt(0) drain __syncthreads() emits.
// Only LDS ordering is needed across the round-loop barriers (see R10 notes).
__device__ __forceinline__ void barrier_lds_only(){
  asm volatile("s_waitcnt vmcnt(63) expcnt(7) lgkmcnt(0)\n\ts_barrier" ::: "memory");
}

// Prologue: depth-0 input projections + bias, px[b,g,row,n] (fp32) into ws.
__global__ __launch_bounds__(64) void proj0_kernel(
  const float* __restrict__ src, const float* __restrict__ trg,
  const float* __restrict__ Wix, const float* __restrict__ Wiy,
  const float* __restrict__ bx, const float* __restrict__ by,
  float* __restrict__ ws)
{
  const int row = blockIdx.x, g = blockIdx.y, b = blockIdx.z;
  const int n = threadIdx.x;
  const float* x = (g == 0) ? (src + (b*Sn + row)*Hn) : (trg + (b*Tn + row)*Hn);
  const float* W = (g == 0) ? Wix : Wiy;   // depth-0 slice
  float a = (g == 0) ? bx[n] : by[n];      // depth-0 bias folded in
  #pragma unroll 8
  for (int f = 0; f < Hn; ++f) a = fmaf(x[f], W[f*Hn + n], a);
  ws[((size_t)(b*2 + g)*Sn + row)*Hn + n] = a;
}

// Fused lag-1 wavefront, 1024 threads = 16 waves: wave = (g, nh, ms, dep).
//   g   = stream (0: hx writes col state sX; 1: hy writes row state sY)
//   nh  = 32-feature half; computed as 2 n-subtiles v=0,1 sharing ONE set of
//         state B-fragment reads (the duplication cut vs R10's (g,nt,dep))
//   ms  = mtile parity: handles mtiles {ms, ms+2, ms+4}
//   dep = depth; round r: dep0 does diag r, dep1 does diag r-1.
// LAUNCH BOUNDS NOTE: second arg is MIN BLOCKS PER CU (CUDA semantics).
// (1024,4) made the compiler budget 64 waves -> clamp -> 64-VGPR cap -> the
// R11 inner-loop spills. (1024,1) -> 16 waves -> 128-VGPR budget, no spills;
// occupancy is 1 block/CU anyway (110KB LDS).
__global__ __launch_bounds__(1024, 1) void grid_rnn_fused(
  const float* __restrict__ Whx, const float* __restrict__ Why,
  const float* __restrict__ Wix, const float* __restrict__ Wiy,
  const float* __restrict__ bx,  const float* __restrict__ by,
  const int* __restrict__ src_lens, const int* __restrict__ trg_lens,
  float* __restrict__ out, const float* __restrict__ ws)
{
  extern __shared__ u16 smem[];
  // layout: [X0hi][X0lo][Y0hi][Y0lo][X1hi][X1lo][Y1hi][Y1lo]
  u16* const sXhi0 = smem;           u16* const sXlo0 = smem + ARR;
  u16* const sYhi0 = smem + 2*ARR;   u16* const sYlo0 = smem + 3*ARR;
  u16* const sXhi1 = smem + 4*ARR;   u16* const sXlo1 = smem + 5*ARR;
  u16* const sYhi1 = smem + 6*ARR;   u16* const sYlo1 = smem + 7*ARR;

  const int b    = blockIdx.x;
  const int tid  = threadIdx.x;
  const int lane = tid & 63;
  const int wid  = tid >> 6;
  const int q    = lane >> 4;
  const int c    = lane & 15;
  const int dep  = wid & 1;
  const int ms   = (wid >> 1) & 1;
  const int nh   = (wid >> 2) & 1;
  const int g    = wid >> 3;
  const int sl = src_lens[b], tl = trg_lens[b];

  u16* const mXhi = dep ? sXhi1 : sXhi0;  u16* const mXlo = dep ? sXlo1 : sXlo0;
  u16* const mYhi = dep ? sYhi1 : sYhi0;  u16* const mYlo = dep ? sYlo1 : sYlo0;
  u16* const pHi = (g == 0) ? sXhi0 : sYhi0;   // depth-0 state for dep1 projection
  u16* const pLo = (g == 0) ? sXlo0 : sYlo0;

  for (int idx = tid; idx < (8*ARR)/2; idx += 1024) ((u32*)smem)[idx] = 0u;

  // ---- weights (own depth, own 32-feature half = 2 subtiles), hi/lo bf16 split
  const float* Wh = (g == 0 ? Whx : Why) + dep*H2n*Hn;
  i32x4 whf_h[2][4], whf_l[2][4];
  #pragma unroll
  for (int v = 0; v < 2; ++v){
    const int nb = nh*32 + v*16 + c;
    #pragma unroll
    for (int kk = 0; kk < 4; ++kk){
      #pragma unroll
      for (int p = 0; p < 4; ++p){
        float w0 = Wh[(kk*32 + q*8 + 2*p    )*Hn + nb];
        float w1 = Wh[(kk*32 + q*8 + 2*p + 1)*Hn + nb];
        u32 h0_ = f2bf_rne(w0), h1_ = f2bf_rne(w1);
        u32 l0_ = f2bf_rne(w0 - bf2f((u16)h0_));
        u32 l1_ = f2bf_rne(w1 - bf2f((u16)h1_));
        whf_h[v][kk][p] = (int)(h0_ | (h1_ << 16));
        whf_l[v][kk][p] = (int)(l0_ | (l1_ << 16));
      }
    }
  }
  const float* Wi = (g == 0 ? Wix : Wiy) + Hn*Hn;  // depth-1 slice (dep1 only)
  i32x4 wif_h[2][2], wif_l[2][2];
  #pragma unroll
  for (int v = 0; v < 2; ++v){
    const int nb = nh*32 + v*16 + c;
    #pragma unroll
    for (int kk = 0; kk < 2; ++kk){
      #pragma unroll
      for (int p = 0; p < 4; ++p){
        float w0 = Wi[(kk*32 + q*8 + 2*p    )*Hn + nb];
        float w1 = Wi[(kk*32 + q*8 + 2*p + 1)*Hn + nb];
        u32 h0_ = f2bf_rne(w0), h1_ = f2bf_rne(w1);
        u32 l0_ = f2bf_rne(w0 - bf2f((u16)h0_));
        u32 l1_ = f2bf_rne(w1 - bf2f((u16)h1_));
        wif_h[v][kk][p] = (int)(h0_ | (h1_ << 16));
        wif_l[v][kk][p] = (int)(l0_ | (l1_ << 16));
      }
    }
  }
  f32x4 bias4[2];  // depth-1 bias (dep0 gets bias via ws projections)
  #pragma unroll
  for (int v = 0; v < 2; ++v){
    const float* bb = (g == 0 ? bx : by) + dep*Hn;
    #pragma unroll
    for (int r4 = 0; r4 < 4; ++r4) bias4[v][r4] = bb[nh*32 + v*16 + q*4 + r4];
  }
  const float* pxbase = ws + (size_t)(b*2 + g)*Sn*Hn;

  __syncthreads();   // full barrier once: init + weights visible

  for (int r = 0; r < NROUND; ++r){
    const int myd  = r - dep;
    const bool wact = (myd >= 0) && (myd < NDIAG);
    const int i0 = (myd > Tn-1) ? myd - (Tn-1) : 0;
    const int i1 = (myd < Sn-1) ? myd : Sn-1;
    const int nc = i1 - i0 + 1;
    const int mtiles = (nc + 15) >> 4;

    u32x2 hvp[3][2], lvp[3][2];   // packed hi/lo results carried across the barrier

    // ---- C phase: read old state, compute; NO state writes
    #pragma unroll
    for (int u = 0; u < 3; ++u){
      const int mt = ms + 2*u;
      const bool act = wact && (mt < mtiles);
      if (!act) continue;
      const int cell = mt*16 + c;
      const int cc = (cell < nc) ? cell : nc - 1;
      const int i = i0 + cc, j = myd - i;

      f32x4 acc[2];
      if (dep == 0){
        const float* pxp = pxbase + (size_t)((g == 0) ? i : j)*Hn + nh*32 + q*4;
        acc[0] = *(const f32x4*)(pxp);
        acc[1] = *(const f32x4*)(pxp + 16);
      } else {
        acc[0] = bias4[0];
        acc[1] = bias4[1];
      }
      // recurrence: K=128 (kk0-1: hx from col j; kk2-3: hy from row i)
      // state fragments read ONCE, used by both 16-feature subtiles
      #pragma unroll
      for (int kk = 0; kk < 4; ++kk){
        const int off = (kk < 2) ? (j*STR + kk*32 + q*8) : (i*STR + (kk-2)*32 + q*8);
        const u16* hb_ = (kk < 2) ? mXhi : mYhi;
        const u16* lb_ = (kk < 2) ? mXlo : mYlo;
        i32x4 shi = *(const i32x4*)(hb_ + off);
        i32x4 slo = *(const i32x4*)(lb_ + off);
        #pragma unroll
        for (int v = 0; v < 2; ++v){
          acc[v] = __builtin_amdgcn_mfma_f32_16x16x32_bf16(
                     __builtin_bit_cast(bf16x8, whf_h[v][kk]),
                     __builtin_bit_cast(bf16x8, shi), acc[v], 0, 0, 0);
          acc[v] = __builtin_amdgcn_mfma_f32_16x16x32_bf16(
                     __builtin_bit_cast(bf16x8, whf_h[v][kk]),
                     __builtin_bit_cast(bf16x8, slo), acc[v], 0, 0, 0);
          acc[v] = __builtin_amdgcn_mfma_f32_16x16x32_bf16(
                     __builtin_bit_cast(bf16x8, whf_l[v][kk]),
                     __builtin_bit_cast(bf16x8, shi), acc[v], 0, 0, 0);
        }
      }
      // depth-1 projection: operand = depth-0 h at (i,j) straight from LDS
      if (dep == 1){
        const int pr = ((g == 0) ? j : i)*STR;
        #pragma unroll
        for (int kk = 0; kk < 2; ++kk){
          i32x4 ph = *(const i32x4*)(pHi + pr + kk*32 + q*8);
          i32x4 pl = *(const i32x4*)(pLo + pr + kk*32 + q*8);
          #pragma unroll
          for (int v = 0; v < 2; ++v){
            acc[v] = __builtin_amdgcn_mfma_f32_16x16x32_bf16(
                       __builtin_bit_cast(bf16x8, wif_h[v][kk]),
                       __builtin_bit_cast(bf16x8, ph), acc[v], 0, 0, 0);
            acc[v] = __builtin_amdgcn_mfma_f32_16x16x32_bf16(
                       __builtin_bit_cast(bf16x8, wif_h[v][kk]),
                       __builtin_bit_cast(bf16x8, pl), acc[v], 0, 0, 0);
            acc[v] = __builtin_amdgcn_mfma_f32_16x16x32_bf16(
                       __builtin_bit_cast(bf16x8, wif_l[v][kk]),
                       __builtin_bit_cast(bf16x8, ph), acc[v], 0, 0, 0);  // W_lo*h_hi
          }
        }
      }
      // tanh -> HW packed hi/lo split (RNE both levels)
      #pragma unroll
      for (int v = 0; v < 2; ++v){
        float h0 = fast_tanh(acc[v][0]), h1 = fast_tanh(acc[v][1]);
        float h2 = fast_tanh(acc[v][2]), h3 = fast_tanh(acc[v][3]);
        u32 hv01 = cvt_pk_bf16(h0, h1);
        u32 hv23 = cvt_pk_bf16(h2, h3);
        hvp[u][v][0] = hv01; hvp[u][v][1] = hv23;
        lvp[u][v][0] = cvt_pk_bf16(h0 - lo16f(hv01), h1 - hi16f(hv01));
        lvp[u][v][1] = cvt_pk_bf16(h2 - lo16f(hv23), h3 - hi16f(hv23));
      }
    }
    barrier_lds_only();

    // ---- W phase: write state + masked global outputs
    #pragma unroll
    for (int u = 0; u < 3; ++u){
      const int mt = ms + 2*u;
      const bool act = wact && (mt < mtiles);
      const int cell = mt*16 + c;
      if (!act || cell >= nc) continue;
      const int i = i0 + cell, j = myd - i;
      const bool mok = (i < sl) && (j < tl);
      u16* st_hiB = (g == 0) ? (mXhi + j*STR) : (mYhi + i*STR);
      u16* st_loB = (g == 0) ? (mXlo + j*STR) : (mYlo + i*STR);
      float* outB = out + ((size_t)((g*2 + dep)*Bn + b)*(Sn*Tn) + i*Tn + j)*Hn;
      #pragma unroll
      for (int v = 0; v < 2; ++v){
        const int n0 = nh*32 + v*16 + q*4;
        *(u32x2*)(st_hiB + n0) = hvp[u][v];
        *(u32x2*)(st_loB + n0) = lvp[u][v];
        f32x4 ov;
        ov[0] = lo16f(hvp[u][v][0]) + lo16f(lvp[u][v][0]);
        ov[1] = hi16f(hvp[u][v][0]) + hi16f(lvp[u][v][0]);
        ov[2] = lo16f(hvp[u][v][1]) + lo16f(lvp[u][v][1]);
        ov[3] = hi16f(hvp[u][v][1]) + hi16f(lvp[u][v][1]);
        if (!mok) ov = (f32x4)(0.f);
        *(f32x4*)(outB + n0) = ov;
      }
    }
    barrier_lds_only();
  }
}

extern "C" void kernel_launch(void* const* d_in, const int* in_sizes, int n_in,
                              void* d_out, int out_size, void* d_ws, size_t ws_size,
                              hipStream_t stream) {
  (void)in_sizes; (void)n_in; (void)out_size; (void)ws_size;
  (void)hipFuncSetAttribute((const void*)grid_rnn_fused,
                            hipFuncAttributeMaxDynamicSharedMemorySize, 8*ARR*2);
  proj0_kernel<<<dim3(Sn, 2, Bn), 64, 0, stream>>>(
      (const float*)d_in[0], (const float*)d_in[1],
      (const float*)d_in[2], (const float*)d_in[5],
      (const float*)d_in[4], (const float*)d_in[7],
      (float*)d_ws);
  grid_rnn_fused<<<dim3(Bn), dim3(1024), 8*ARR*2, stream>>>(
      (const float*)d_in[3], (const float*)d_in[6],
      (const float*)d_in[2], (const float*)d_in[5],
      (const float*)d_in[4], (const float*)d_in[7],
      (const int*)d_in[8], (const int*)d_in[9],
      (float*)d_out, (const float*)d_ws);
}

// Round 13
// 616.470 us; speedup vs baseline: 3.5717x; 3.5717x over previous
//
#include <hip/hip_runtime.h>

typedef unsigned short u16;
typedef unsigned int   u32;
typedef _Float16 f16x8 __attribute__((ext_vector_type(8)));
typedef float  f32x4  __attribute__((ext_vector_type(4)));
typedef int    i32x4  __attribute__((ext_vector_type(4)));
typedef u32    u32x2  __attribute__((ext_vector_type(2)));

#define Bn 8
#define Sn 96
#define Tn 96
#define Hn 64
#define H2n 128
#define NDIAG 191
#define NROUND 192
#define STR 72            // state row stride (u16): 144B, 16B-aligned
#define ARR (Sn*STR)      // 6912 u16 per array; 8 arrays (2 dep x 2 stream x 2 parity) = 110,592 B

__device__ __forceinline__ u32 pack2f16(float a, float b){
  _Float16 ha = (_Float16)a, hb = (_Float16)b;    // v_cvt_f16_f32 (RNE)
  return (u32)__builtin_bit_cast(u16, ha) | ((u32)__builtin_bit_cast(u16, hb) << 16);
}
__device__ __forceinline__ float fast_tanh(float x){
  float y = fminf(fmaxf(x+x, -30.f), 30.f);
  float e = __expf(y);
  return (e-1.f)*__builtin_amdgcn_rcpf(e+1.f);
}
// Workgroup barrier WITHOUT the vmcnt(0) drain __syncthreads() emits:
// only LDS ordering is needed between rounds (out is write-only, px read-only).
__device__ __forceinline__ void barrier_lds_only(){
  asm volatile("s_waitcnt vmcnt(63) expcnt(7) lgkmcnt(0)\n\ts_barrier" ::: "memory");
}

// Prologue: depth-0 input projections + bias, px[b,g,row,n] (fp32) into ws.
__global__ __launch_bounds__(64) void proj0_kernel(
  const float* __restrict__ src, const float* __restrict__ trg,
  const float* __restrict__ Wix, const float* __restrict__ Wiy,
  const float* __restrict__ bx, const float* __restrict__ by,
  float* __restrict__ ws)
{
  const int row = blockIdx.x, g = blockIdx.y, b = blockIdx.z;
  const int n = threadIdx.x;
  const float* x = (g == 0) ? (src + (b*Sn + row)*Hn) : (trg + (b*Tn + row)*Hn);
  const float* W = (g == 0) ? Wix : Wiy;   // depth-0 slice
  float a = (g == 0) ? bx[n] : by[n];      // depth-0 bias folded in
  #pragma unroll 8
  for (int f = 0; f < Hn; ++f) a = fmaf(x[f], W[f*Hn + n], a);
  ws[((size_t)(b*2 + g)*Sn + row)*Hn + n] = a;
}

// Fused lag-1 wavefront, 1024 threads = 16 waves: wave = (g, nt, dep).
//   g   = stream (0: hx writes col state X; 1: hy writes row state Y)
//   nt  = 16-feature n-tile
//   dep = depth; round r: dep0 does diag r, dep1 does diag r-1.
// State: single fp16, PARITY DOUBLE-BUFFERED — round r writes buf[r&1], reads
// buf[(r-1)&1] (incl. dep1's projection operand from dep0's buffer). This
// removes the W phase: ONE barrier per round, no carry registers.
// Weights: single fp16 (24 VGPRs/wave). Total live regs ~45 < the observed
// 64-VGPR cap for 1024-thread kernels -> no spills (R9/R11/R12 post-mortem).
__global__ __launch_bounds__(1024, 1) void grid_rnn_fused(
  const float* __restrict__ Whx, const float* __restrict__ Why,
  const float* __restrict__ Wix, const float* __restrict__ Wiy,
  const float* __restrict__ bx,  const float* __restrict__ by,
  const int* __restrict__ src_lens, const int* __restrict__ trg_lens,
  float* __restrict__ out, const float* __restrict__ ws)
{
  extern __shared__ u16 smem[];
  // layout per depth d at smem + d*4*ARR: [X p0][X p1][Y p0][Y p1]
  const int b    = blockIdx.x;
  const int tid  = threadIdx.x;
  const int lane = tid & 63;
  const int wid  = tid >> 6;
  const int q    = lane >> 4;
  const int c    = lane & 15;
  const int dep  = wid & 1;
  const int nt   = (wid >> 1) & 3;
  const int g    = wid >> 3;
  const int sl = src_lens[b], tl = trg_lens[b];

  u16* const sXd = smem + dep*4*ARR;            // own-depth X parity pair
  u16* const sYd = smem + dep*4*ARR + 2*ARR;    // own-depth Y parity pair
  u16* const sPr = (g == 0) ? smem : (smem + 2*ARR);  // dep0's X/Y pair (proj source)

  for (int idx = tid; idx < (8*ARR)/2; idx += 1024) ((u32*)smem)[idx] = 0u;

  // ---- weights (own depth, own 16-feature tile), single fp16
  const float* Wh = (g == 0 ? Whx : Why) + dep*H2n*Hn;
  const int nb = nt*16 + c;
  i32x4 whf[4];
  #pragma unroll
  for (int kk = 0; kk < 4; ++kk){
    #pragma unroll
    for (int p = 0; p < 4; ++p){
      float w0 = Wh[(kk*32 + q*8 + 2*p    )*Hn + nb];
      float w1 = Wh[(kk*32 + q*8 + 2*p + 1)*Hn + nb];
      whf[kk][p] = (int)pack2f16(w0, w1);
    }
  }
  const float* Wi = (g == 0 ? Wix : Wiy) + Hn*Hn;  // depth-1 slice (dep1 only)
  i32x4 wif[2];
  #pragma unroll
  for (int kk = 0; kk < 2; ++kk){
    #pragma unroll
    for (int p = 0; p < 4; ++p){
      float w0 = Wi[(kk*32 + q*8 + 2*p    )*Hn + nb];
      float w1 = Wi[(kk*32 + q*8 + 2*p + 1)*Hn + nb];
      wif[kk][p] = (int)pack2f16(w0, w1);
    }
  }
  f32x4 bias4;  // depth-1 bias (dep0 gets bias via ws projections)
  {
    const float* bb = (g == 0 ? bx : by) + dep*Hn;
    #pragma unroll
    for (int r4 = 0; r4 < 4; ++r4) bias4[r4] = bb[nt*16 + q*4 + r4];
  }
  const float* pxbase = ws + (size_t)(b*2 + g)*Sn*Hn;
  float* const outbase = out + (size_t)((g*2 + dep)*Bn + b)*(size_t)(Sn*Tn)*Hn;

  __syncthreads();   // init + weights visible

  for (int r = 0; r < NROUND; ++r){
    const int myd  = r - dep;
    const bool wact = (myd >= 0) && (myd < NDIAG);
    const int i0 = (myd > Tn-1) ? myd - (Tn-1) : 0;
    const int i1 = (myd < Sn-1) ? myd : Sn-1;
    const int nc = i1 - i0 + 1;
    const int mtiles = (nc + 15) >> 4;
    const int cp = r & 1, pp = cp ^ 1;
    const u16* const rdX = sXd + pp*ARR;     // reads: previous parity
    const u16* const rdY = sYd + pp*ARR;
    const u16* const rdP = sPr + pp*ARR;     // dep0 state, previous parity
    u16* const wrS = ((g == 0) ? sXd : sYd) + cp*ARR;   // writes: current parity

    #pragma unroll
    for (int u = 0; u < 6; ++u){
      const bool act = wact && (u < mtiles);
      if (!act) continue;
      const int cell = u*16 + c;
      const int cc = (cell < nc) ? cell : nc - 1;
      const int i = i0 + cc, j = myd - i;

      f32x4 acc;
      if (dep == 0){
        acc = *(const f32x4*)(pxbase + (size_t)((g == 0) ? i : j)*Hn + nt*16 + q*4);
      } else {
        acc = bias4;
      }
      // recurrence: K=128 (kk0-1: hx from col j; kk2-3: hy from row i)
      #pragma unroll
      for (int kk = 0; kk < 4; ++kk){
        const int off = (kk < 2) ? (j*STR + kk*32 + q*8) : (i*STR + (kk-2)*32 + q*8);
        const u16* sb = (kk < 2) ? rdX : rdY;
        i32x4 sv = *(const i32x4*)(sb + off);
        acc = __builtin_amdgcn_mfma_f32_16x16x32_f16(
                __builtin_bit_cast(f16x8, whf[kk]),
                __builtin_bit_cast(f16x8, sv), acc, 0, 0, 0);
      }
      // depth-1 projection: dep0's h(i,j) from its previous-parity state slot
      if (dep == 1){
        const int pr = ((g == 0) ? j : i)*STR;
        #pragma unroll
        for (int kk = 0; kk < 2; ++kk){
          i32x4 pv = *(const i32x4*)(rdP + pr + kk*32 + q*8);
          acc = __builtin_amdgcn_mfma_f32_16x16x32_f16(
                  __builtin_bit_cast(f16x8, wif[kk]),
                  __builtin_bit_cast(f16x8, pv), acc, 0, 0, 0);
        }
      }
      // tanh -> immediate state write (fp16, current parity) + masked out store
      float h0 = fast_tanh(acc[0]), h1 = fast_tanh(acc[1]);
      float h2 = fast_tanh(acc[2]), h3 = fast_tanh(acc[3]);
      if (cell < nc){
        const int n0 = nt*16 + q*4;
        u32x2 hp; hp[0] = pack2f16(h0, h1); hp[1] = pack2f16(h2, h3);
        *(u32x2*)(wrS + ((g == 0) ? j : i)*STR + n0) = hp;
        f32x4 ov = {h0, h1, h2, h3};
        if (i >= sl || j >= tl) ov = (f32x4)(0.f);
        *(f32x4*)(outbase + (size_t)(i*Tn + j)*Hn + n0) = ov;
      }
    }
    barrier_lds_only();   // single barrier per round (parity buffers)
  }
}

extern "C" void kernel_launch(void* const* d_in, const int* in_sizes, int n_in,
                              void* d_out, int out_size, void* d_ws, size_t ws_size,
                              hipStream_t stream) {
  (void)in_sizes; (void)n_in; (void)out_size; (void)ws_size;
  (void)hipFuncSetAttribute((const void*)grid_rnn_fused,
                            hipFuncAttributeMaxDynamicSharedMemorySize, 8*ARR*2);
  proj0_kernel<<<dim3(Sn, 2, Bn), 64, 0, stream>>>(
      (const float*)d_in[0], (const float*)d_in[1],
      (const float*)d_in[2], (const float*)d_in[5],
      (const float*)d_in[4], (const float*)d_in[7],
      (float*)d_ws);
  grid_rnn_fused<<<dim3(Bn), dim3(1024), 8*ARR*2, stream>>>(
      (const float*)d_in[3], (const float*)d_in[6],
      (const float*)d_in[2], (const float*)d_in[5],
      (const float*)d_in[4], (const float*)d_in[7],
      (const int*)d_in[8], (const int*)d_in[9],
      (float*)d_out, (const float*)d_ws);
}